// Round 9
// baseline (313.981 us; speedup 1.0000x reference)
//
#include <hip/hip_runtime.h>

typedef unsigned short u16;
typedef unsigned int u32;
typedef __attribute__((ext_vector_type(4))) float f32x4;
typedef __attribute__((ext_vector_type(8))) short bf16x8;   // 8 bf16 (4 VGPRs) MFMA frag
typedef __attribute__((ext_vector_type(4))) u16 u16x4;
typedef __attribute__((ext_vector_type(8))) u16 u16x8;

// B=8, S=2048, D=1024
#define NB 8
#define NS 2048
#define ND 1024
#define KC 1280   // cap on padded compact token count (nv ~ 1024 +/- 23; 1280 = +11 sigma)

__device__ __forceinline__ u16 f2bf(float x) {  // f32 -> bf16 round-nearest-even
  u32 u = __builtin_bit_cast(u32, x);
  u32 r = 0x7fffu + ((u >> 16) & 1u);
  return (u16)((u + r) >> 16);
}
__device__ __forceinline__ float bf2f(u16 h) {
  return __builtin_bit_cast(float, (u32)h << 16);
}

__device__ __forceinline__ void gload16(const void* g, void* l) {
  __builtin_amdgcn_global_load_lds(
      (const __attribute__((address_space(1))) void*)g,
      (__attribute__((address_space(3))) void*)l, 16, 0, 0);
}

// ---------------- mask scan: per batch build idx (compact->full), pos (full->compact), nv ----
__global__ __launch_bounds__(256) void scan_kernel(
    const float* __restrict__ mask, u16* __restrict__ idx, u16* __restrict__ pos,
    int* __restrict__ nv, int* __restrict__ nvp) {
  const int b = blockIdx.x, t = threadIdx.x;
  const float* m = mask + (size_t)b * NS;
  int mv[8], mysum = 0;
#pragma unroll
  for (int j = 0; j < 8; ++j) { mv[j] = (m[t * 8 + j] != 0.f) ? 1 : 0; mysum += mv[j]; }
  const int lane = t & 63, wv = t >> 6;
  int incl = mysum;
#pragma unroll
  for (int o = 1; o < 64; o <<= 1) {
    int v = __shfl_up(incl, o);
    if (lane >= o) incl += v;
  }
  __shared__ int wsum[4];
  if (lane == 63) wsum[wv] = incl;
  __syncthreads();
  int woff = 0;
#pragma unroll
  for (int i = 0; i < 4; ++i) woff += (i < wv) ? wsum[i] : 0;
  const int total = wsum[0] + wsum[1] + wsum[2] + wsum[3];
  int off = woff + incl - mysum;
#pragma unroll
  for (int j = 0; j < 8; ++j) {
    const int tt = t * 8 + j;
    pos[(size_t)b * NS + tt] = (u16)off;
    if (mv[j]) { idx[(size_t)b * NS + off] = (u16)tt; off++; }
  }
  __syncthreads();
  for (int j = total + t; j < KC; j += 256) idx[(size_t)b * NS + j] = 0;  // pad: valid row 0
  if (t == 0) {
    nv[b] = total;
    int p = (total + 255) & ~255;
    if (p > KC) p = KC;
    if (p < 256) p = 256;
    nvp[b] = p;
  }
}

// ------- fused compact split into "hl" layout: text & text1 gathered to KC rows, + W -------
// dst row j (< KC) = split of src full row idx[b][j]; pad rows duplicate row 0 (finite,
// masked downstream). hl layout: hi at r*2048 + (k>>5)*64 + (k&31), lo at +32.
__device__ __forceinline__ void split_chunk(const float* __restrict__ srcRow,
                                            u16* __restrict__ dstRow, int kc) {
  f32x4 v0 = *(const f32x4*)(srcRow + kc);
  f32x4 v1 = *(const f32x4*)(srcRow + kc + 4);
  u16x8 h, l;
#pragma unroll
  for (int j = 0; j < 4; ++j) {
    u16 a = f2bf(v0[j]);
    h[j] = a;
    l[j] = f2bf(v0[j] - bf2f(a));
    u16 bb = f2bf(v1[j]);
    h[j + 4] = bb;
    l[j + 4] = f2bf(v1[j] - bf2f(bb));
  }
  const int off = ((kc >> 5) << 6) + (kc & 31);
  *(u16x8*)&dstRow[off] = h;
  *(u16x8*)&dstRow[off + 32] = l;
}

__global__ __launch_bounds__(256) void split_compact_kernel(
    const float* __restrict__ text, const float* __restrict__ t1, const float* __restrict__ W,
    const u16* __restrict__ idx,
    u16* __restrict__ text_c, u16* __restrict__ t1_c, u16* __restrict__ W_hl) {
  const int UB = KC * (ND / 8);            // units per batch (row-chunks of 8)
  const int U1 = NB * UB;                  // text units
  const int U2 = U1 + NB * UB;             // + t1
  const int U3 = U2 + ND * (ND / 8);       // + W
  int i = blockIdx.x * 256 + threadIdx.x;
  const int stride = gridDim.x * 256;
  for (; i < U3; i += stride) {
    if (i < U2) {
      const float* src = (i < U1) ? text : t1;
      u16* dst = (i < U1) ? text_c : t1_c;
      const int ii = (i < U1) ? i : i - U1;
      const int b = ii / UB;
      const int within = ii - b * UB;
      const int row = within >> 7;
      const int kc = (within & 127) << 3;
      const int srow = idx[(size_t)b * NS + row];
      split_chunk(src + ((size_t)b * NS + srow) * ND,
                  dst + ((size_t)b * KC + row) * 2048, kc);
    } else {
      const int ii = i - U2;
      const int row = ii >> 7;
      const int kc = (ii & 127) << 3;
      split_chunk(W + (size_t)row * ND, W_hl + (size_t)row * 2048, kc);
    }
  }
}

// ---------------- gather-transpose: t1Tc[b][d][j] = bf16(text1[b][idx[j]][d]), 0 if j>=nv ----
__global__ __launch_bounds__(256) void gtrans_kernel(
    const float* __restrict__ t1, const u16* __restrict__ idx,
    const int* __restrict__ nv, u16* __restrict__ t1Tc) {
  __shared__ float tile[32][33];
  const int b = blockIdx.z;
  const int j0 = blockIdx.x * 32, d0 = blockIdx.y * 32;
  const int tx = threadIdx.x, ty = threadIdx.y;  // (32,8)
  const int nvb = nv[b];
#pragma unroll
  for (int k = 0; k < 4; ++k) {
    const int j = j0 + ty + 8 * k;
    const int sr = (j < nvb) ? (int)idx[(size_t)b * NS + j] : 0;
    tile[ty + 8 * k][tx] = (j < nvb) ? t1[((size_t)b * NS + sr) * ND + d0 + tx] : 0.f;
  }
  __syncthreads();
#pragma unroll
  for (int k = 0; k < 4; ++k)
    t1Tc[((size_t)b * ND + d0 + ty + 8 * k) * KC + j0 + tx] = f2bf(tile[tx][ty + 8 * k]);
}

// ============ compact GEMM: 256x256 tile, 8 waves (2M x 4N), dbuf + global_load_lds =======
// R8 structure + T4 counted vmcnt: per step, issue next tile's 8 per-wave gload16 into
// buf^1, then s_waitcnt vmcnt(8) (certifies THIS tile's loads, issued a full step ago,
// while next tile's 8 stay in flight) + raw barrier; compute; plain barrier (protects
// buffer overwrite, no drain). T5 setprio around MFMA cluster.
// LDS tiles [256 rows][64 u16], chunk c of row r at byte r*128 + 16*(c ^ (r&7)) (XOR
// swizzle; 0 bank conflicts); per-lane GLOBAL source pre-swizzled to compensate.
// MODE 0 (K1): A=text_c, B=W_hl, 3-term split MFMA, out qc (compact hl).
// MODE 1 (K2): A=qc, B=t1_c, 3-term, out logitsC f32 compact.
// MODE 2 (PV): A=abf bf16, B=t1Tc bf16, 2xK MFMA, dynamic K, out0 scatter + bias.
template <int MODE>
__global__ __launch_bounds__(512, 2) void gemm_c_kernel(
    const u16* __restrict__ A, const u16* __restrict__ B,
    const u16* __restrict__ idx, const int* __restrict__ nv, const int* __restrict__ nvp,
    u16* __restrict__ outQ, float* __restrict__ outF, const float* __restrict__ bias) {
  constexpr int nTN = (MODE == 1) ? (KC / 256) : (ND / 256);
  constexpr int rowLen = (MODE == 2) ? KC : 2048;
  __shared__ __align__(16) u16 lds[2][2][16384];  // [dbuf][A/B][256*64] = 128 KiB
  const int t = threadIdx.x;
  const int bz = blockIdx.y;
  // XCD-aware bijective swizzle (m204 general form, any grid size)
  const int n = gridDim.x;
  const int q8 = n >> 3, r8 = n & 7, xb = (int)blockIdx.x & 7, kb = (int)blockIdx.x >> 3;
  const int xs = (xb < r8 ? xb * (q8 + 1) : r8 * (q8 + 1) + (xb - r8) * q8) + kb;
  const int tm = xs / nTN, tn = xs % nTN;
  const int rowA0 = tm * 256, rowB0 = tn * 256;
  const int nvpb = nvp[bz];
  if (rowA0 >= nvpb) return;
  if (MODE == 1 && rowB0 >= nvpb) return;

  const int lane = t & 63, w = t >> 6;   // 8 waves: 2M x 4N
  const int wr = w >> 2, wc = w & 3;
  const int fr = lane & 15, fq = lane >> 4;

  // staging: wave w covers rows w*32 + j*8 + lr; lane loads chunk (lane&7)^lr
  const int lr = lane >> 3;
  const int ch = (lane & 7) ^ lr;
  const int ra = rowA0 + w * 32 + lr;
  const int rb = rowB0 + w * 32 + lr;
  const u16* pA0;
  const u16* pB0;
  if (MODE == 0) {
    pA0 = A + ((size_t)bz * KC + ra) * rowLen + ch * 8;   // text_c
    pB0 = B + (size_t)rb * rowLen + ch * 8;               // W (no batch)
  } else if (MODE == 1) {
    pA0 = A + ((size_t)bz * KC + ra) * rowLen + ch * 8;   // qc
    pB0 = B + ((size_t)bz * KC + rb) * rowLen + ch * 8;   // t1_c
  } else {
    pA0 = A + ((size_t)bz * KC + ra) * rowLen + ch * 8;   // abf
    pB0 = B + ((size_t)bz * ND + rb) * rowLen + ch * 8;   // t1Tc
  }

  const int swz = (fr & 7) << 4;
  const int aOff = ((wr * 128 + fr) << 7) + ((fq << 4) ^ swz);
  const int bOff = ((wc * 64 + fr) << 7) + ((fq << 4) ^ swz);

  f32x4 acc[8][4] = {};

  const int nsteps = (MODE == 2) ? (nvpb >> 6) : 32;

  // prologue: stage tile 0 into buf 0 (8 gload16 per wave)
#pragma unroll
  for (int j = 0; j < 4; ++j)
    gload16(pA0 + (size_t)(j * 8) * rowLen, (char*)&lds[0][0][0] + w * 4096 + j * 1024);
#pragma unroll
  for (int j = 0; j < 4; ++j)
    gload16(pB0 + (size_t)(j * 8) * rowLen, (char*)&lds[0][1][0] + w * 4096 + j * 1024);

#pragma unroll 2
  for (int s = 0; s < nsteps; ++s) {
    const int cur = s & 1;
    if (s + 1 < nsteps) {
      // issue next tile's 8 loads (into the other buffer), then certify THIS tile:
      // per-wave outstanding = 8 (tile s, old) + 8 (tile s+1, new); vmcnt(8) waits
      // only for the old 8 while the new 8 stay in flight across compute.
#pragma unroll
      for (int j = 0; j < 4; ++j)
        gload16(pA0 + (size_t)(j * 8) * rowLen + (s + 1) * 64,
                (char*)&lds[cur ^ 1][0][0] + w * 4096 + j * 1024);
#pragma unroll
      for (int j = 0; j < 4; ++j)
        gload16(pB0 + (size_t)(j * 8) * rowLen + (s + 1) * 64,
                (char*)&lds[cur ^ 1][1][0] + w * 4096 + j * 1024);
      asm volatile("s_waitcnt vmcnt(8)" ::: "memory");
    } else {
      asm volatile("s_waitcnt vmcnt(0)" ::: "memory");
    }
    __builtin_amdgcn_s_barrier();          // tile s certified for all waves
    __builtin_amdgcn_sched_barrier(0);     // keep ds_reads below the barrier

    const char* bAc = (const char*)&lds[cur][0][0];
    const char* bBc = (const char*)&lds[cur][1][0];
    bf16x8 b0[4], b1[4];
#pragma unroll
    for (int ni = 0; ni < 4; ++ni) {
      const int ba = bOff + (ni << 11);
      b0[ni] = *(const bf16x8*)(bBc + ba);          // hi (split) / k 0..31 (pv)
      b1[ni] = *(const bf16x8*)(bBc + (ba ^ 64));   // lo (split) / k 32..63 (pv)
    }
    __builtin_amdgcn_s_setprio(1);
#pragma unroll
    for (int mi = 0; mi < 8; ++mi) {
      const int aa = aOff + (mi << 11);
      bf16x8 a0 = *(const bf16x8*)(bAc + aa);
      bf16x8 a1 = *(const bf16x8*)(bAc + (aa ^ 64));
#pragma unroll
      for (int ni = 0; ni < 4; ++ni) {
        if (MODE < 2) {
          acc[mi][ni] = __builtin_amdgcn_mfma_f32_16x16x32_bf16(a0, b0[ni], acc[mi][ni], 0, 0, 0);
          acc[mi][ni] = __builtin_amdgcn_mfma_f32_16x16x32_bf16(a0, b1[ni], acc[mi][ni], 0, 0, 0);
          acc[mi][ni] = __builtin_amdgcn_mfma_f32_16x16x32_bf16(a1, b0[ni], acc[mi][ni], 0, 0, 0);
        } else {
          acc[mi][ni] = __builtin_amdgcn_mfma_f32_16x16x32_bf16(a0, b0[ni], acc[mi][ni], 0, 0, 0);
          acc[mi][ni] = __builtin_amdgcn_mfma_f32_16x16x32_bf16(a1, b1[ni], acc[mi][ni], 0, 0, 0);
        }
      }
    }
    __builtin_amdgcn_s_setprio(0);
    __builtin_amdgcn_s_barrier();          // all reads of buf[cur] done -> next iter may restage it
  }

  // C/D layout (verified m89/m91): col = lane&15, row = (lane>>4)*4 + reg
  const int growBase = rowA0 + wr * 128 + fq * 4;
  const int gcolBase = rowB0 + wc * 64 + fr;
  const int nvb = nv[bz];
#pragma unroll
  for (int mi = 0; mi < 8; ++mi)
#pragma unroll
    for (int ni = 0; ni < 4; ++ni) {
      const int gc = gcolBase + ni * 16;
      float bv = 0.f;
      if (MODE == 2) bv = bias[gc];
#pragma unroll
      for (int r = 0; r < 4; ++r) {
        const int gr = growBase + mi * 16 + r;
        const float v = acc[mi][ni][r];
        if (MODE == 0) {
          const size_t base = ((size_t)bz * KC + gr) * 2048 + ((gc >> 5) << 6) + (gc & 31);
          const u16 h = f2bf(v);
          outQ[base] = h;
          outQ[base + 32] = f2bf(v - bf2f(h));
        } else if (MODE == 1) {
          outF[((size_t)bz * KC + gr) * KC + gc] = v;            // compact logits
        } else {
          if (gr < nvb) {
            const int sf = idx[(size_t)bz * NS + gr];
            outF[((size_t)bz * NS + sf) * 1024 + gc] = v + bv;   // scatter out0 row
          }
        }
      }
    }
}

// -------- softmax over compact logits; expand to full attn row; bias for masked rows --------
__global__ __launch_bounds__(256) void softmax_expand_kernel(
    const float* __restrict__ logitsC, const float* __restrict__ mask,
    const float* __restrict__ bias, float* __restrict__ out0, float* __restrict__ attn,
    const u16* __restrict__ pos, const int* __restrict__ nv, u16* __restrict__ abf) {
  const int row = blockIdx.x, b = row >> 11, s = row & 2047, t = threadIdx.x;
  float* p = attn + (size_t)row * NS;
  const float qm = mask[((size_t)b << 11) + s];
  if (qm == 0.f) {
    f32x4 z = {0.f, 0.f, 0.f, 0.f};
    ((f32x4*)p)[2 * t] = z;
    ((f32x4*)p)[2 * t + 1] = z;
    float* o = out0 + (((size_t)b << 11) + s) * ND;
    ((f32x4*)o)[t] = ((const f32x4*)bias)[t];
    return;
  }
  const int nvb = nv[b];
  const int jq = pos[((size_t)b << 11) + s];
  const float* lrow = logitsC + ((size_t)b * KC + jq) * KC;
  float v[8];
#pragma unroll
  for (int j = 0; j < 8; ++j) {
    const int jj = t * 8 + j;
    v[j] = (jj < nvb) ? lrow[jj] : -3.0e38f;
  }
  float mx = v[0];
#pragma unroll
  for (int j = 1; j < 8; ++j) mx = fmaxf(mx, v[j]);
#pragma unroll
  for (int o = 32; o > 0; o >>= 1) mx = fmaxf(mx, __shfl_xor(mx, o));
  __shared__ float red[4];
  __shared__ float esm[KC];
  if ((t & 63) == 0) red[t >> 6] = mx;
  __syncthreads();
  mx = fmaxf(fmaxf(red[0], red[1]), fmaxf(red[2], red[3]));
  float e[8];
  float sum = 0.f;
#pragma unroll
  for (int j = 0; j < 8; ++j) {
    e[j] = (t * 8 + j < nvb) ? __expf(v[j] - mx) : 0.f;
    sum += e[j];
  }
#pragma unroll
  for (int o = 32; o > 0; o >>= 1) sum += __shfl_xor(sum, o);
  __syncthreads();
  if ((t & 63) == 0) red[t >> 6] = sum;
  __syncthreads();
  sum = red[0] + red[1] + red[2] + red[3];
  const float sc = 1.0f / sum;
  if (t < KC / 8) {
    u16x8 ub;
#pragma unroll
    for (int j = 0; j < 8; ++j) {
      const float ev = e[j] * sc;
      esm[t * 8 + j] = ev;
      ub[j] = f2bf(ev);
    }
    *(u16x8*)(abf + ((size_t)b * KC + jq) * KC + t * 8) = ub;
  }
  __syncthreads();
  const float* km = mask + ((size_t)b << 11);
  const u16* pp = pos + ((size_t)b << 11);
  const u16x8 pv8 = *(const u16x8*)&pp[t * 8];
  const f32x4 km0 = ((const f32x4*)km)[2 * t];
  const f32x4 km1 = ((const f32x4*)km)[2 * t + 1];
#pragma unroll
  for (int h = 0; h < 2; ++h) {
    const f32x4 kmv = h ? km1 : km0;
    f32x4 ov;
#pragma unroll
    for (int j = 0; j < 4; ++j) {
      int ip = pv8[h * 4 + j];
      if (ip >= KC) ip = 0;  // speculation-safe clamp (valid tokens always < nv <= KC)
      ov[j] = (kmv[j] != 0.f) ? esm[ip] : 0.f;
    }
    ((f32x4*)p)[2 * t + h] = ov;
  }
}

extern "C" void kernel_launch(void* const* d_in, const int* in_sizes, int n_in,
                              void* d_out, int out_size, void* d_ws, size_t ws_size,
                              hipStream_t stream) {
  const float* text = (const float*)d_in[0];
  const float* text1 = (const float*)d_in[1];
  const float* mask = (const float*)d_in[2];
  const float* W = (const float*)d_in[3];
  const float* bias = (const float*)d_in[4];

  float* out0 = (float*)d_out;                       // [8,2048,1024] f32
  float* attn = out0 + (size_t)NB * NS * ND;         // [8,2048,2048] f32

  // choreography:
  //  attn region: text_c (40MB compact hl) -> K1 consumes -> softmax writes full attn rows
  //  out0 region: qc (compact q hl, 40MB) -> dead after K2 -> PV + softmax write out0
  //  ws: t1_c(40MB) | W_hl(4MB) | t1Tc(21MB) | logitsC(52MB) | idx/pos/nv/nvp;
  //      abf (26MB) overlays t1_c (dead after K2)
  u16* text_c = (u16*)attn;                           // [8][KC][2048]
  u16* qc = (u16*)out0;                               // [8][KC][2048]
  u16* wsp = (u16*)d_ws;
  u16* t1_c = wsp;                                    // [8][KC][2048]
  u16* W_hl = t1_c + (size_t)NB * KC * 2048;          // [1024][2048]
  u16* t1Tc = W_hl + (size_t)ND * 2048;               // [8][1024][KC]
  float* logitsC = (float*)(t1Tc + (size_t)NB * ND * KC);  // [8][KC][KC] f32
  u16* idx = (u16*)(logitsC + (size_t)NB * KC * KC);  // [8][2048]
  u16* pos = idx + (size_t)NB * NS;                   // [8][2048]
  int* nv = (int*)(pos + (size_t)NB * NS);            // [8]
  int* nvp = nv + NB;                                 // [8]
  u16* abf = t1_c;                                    // [8][KC][KC] bf16, overlays t1_c

  scan_kernel<<<NB, 256, 0, stream>>>(mask, idx, pos, nv, nvp);
  split_compact_kernel<<<2048, 256, 0, stream>>>(text, text1, W, idx, text_c, t1_c, W_hl);
  gtrans_kernel<<<dim3(KC / 32, ND / 32, NB), dim3(32, 8), 0, stream>>>(text1, idx, nv, t1Tc);

  // K1: qc = text_c @ W^T  (M=nvp<=KC compact, N=1024, K=1024) -> qc
  gemm_c_kernel<0><<<dim3((KC / 256) * (ND / 256), NB), 512, 0, stream>>>(
      text_c, W_hl, idx, nv, nvp, qc, nullptr, nullptr);

  // K2: logitsC = qc @ t1_c^T (M,N=nvp compact, K=1024) -> compact f32
  gemm_c_kernel<1><<<dim3((KC / 256) * (KC / 256), NB), 512, 0, stream>>>(
      qc, t1_c, idx, nv, nvp, nullptr, logitsC, nullptr);

  // K3: softmax over compact logits; expand full attn rows; abf compact; bias rows in out0
  softmax_expand_kernel<<<NB * NS, 256, 0, stream>>>(
      logitsC, mask, bias, out0, attn, pos, nv, abf);

  // K4: out0[idx] = abf @ t1Tc^T + bias (M=nvp compact, N=1024, K=nvp compact)
  gemm_c_kernel<2><<<dim3((KC / 256) * (ND / 256), NB), 512, 0, stream>>>(
      abf, t1Tc, idx, nv, nvp, nullptr, out0, bias);
}

// Round 10
// 292.110 us; speedup vs baseline: 1.0749x; 1.0749x over previous
//
#include <hip/hip_runtime.h>

typedef unsigned short u16;
typedef unsigned int u32;
typedef __attribute__((ext_vector_type(4))) float f32x4;
typedef __attribute__((ext_vector_type(8))) short bf16x8;   // 8 bf16 (4 VGPRs) MFMA frag
typedef __attribute__((ext_vector_type(4))) u16 u16x4;
typedef __attribute__((ext_vector_type(8))) u16 u16x8;

// B=8, S=2048, D=1024
#define NB 8
#define NS 2048
#define ND 1024
#define KC 1280   // cap on padded compact token count (nv ~ 1024 +/- 23; 1280 = +11 sigma)

__device__ __forceinline__ u16 f2bf(float x) {  // f32 -> bf16 round-nearest-even
  u32 u = __builtin_bit_cast(u32, x);
  u32 r = 0x7fffu + ((u >> 16) & 1u);
  return (u16)((u + r) >> 16);
}
__device__ __forceinline__ float bf2f(u16 h) {
  return __builtin_bit_cast(float, (u32)h << 16);
}

__device__ __forceinline__ void gload16(const void* g, void* l) {
  __builtin_amdgcn_global_load_lds(
      (const __attribute__((address_space(1))) void*)g,
      (__attribute__((address_space(3))) void*)l, 16, 0, 0);
}

// ---------------- mask scan: per batch build idx (compact->full), pos (full->compact), nv ----
__global__ __launch_bounds__(256) void scan_kernel(
    const float* __restrict__ mask, u16* __restrict__ idx, u16* __restrict__ pos,
    int* __restrict__ nv, int* __restrict__ nvp) {
  const int b = blockIdx.x, t = threadIdx.x;
  const float* m = mask + (size_t)b * NS;
  int mv[8], mysum = 0;
#pragma unroll
  for (int j = 0; j < 8; ++j) { mv[j] = (m[t * 8 + j] != 0.f) ? 1 : 0; mysum += mv[j]; }
  const int lane = t & 63, wv = t >> 6;
  int incl = mysum;
#pragma unroll
  for (int o = 1; o < 64; o <<= 1) {
    int v = __shfl_up(incl, o);
    if (lane >= o) incl += v;
  }
  __shared__ int wsum[4];
  if (lane == 63) wsum[wv] = incl;
  __syncthreads();
  int woff = 0;
#pragma unroll
  for (int i = 0; i < 4; ++i) woff += (i < wv) ? wsum[i] : 0;
  const int total = wsum[0] + wsum[1] + wsum[2] + wsum[3];
  int off = woff + incl - mysum;
#pragma unroll
  for (int j = 0; j < 8; ++j) {
    const int tt = t * 8 + j;
    pos[(size_t)b * NS + tt] = (u16)off;
    if (mv[j]) { idx[(size_t)b * NS + off] = (u16)tt; off++; }
  }
  __syncthreads();
  for (int j = total + t; j < KC; j += 256) idx[(size_t)b * NS + j] = 0;  // pad: valid row 0
  if (t == 0) {
    nv[b] = total;
    int p = (total + 255) & ~255;
    if (p > KC) p = KC;
    if (p < 256) p = 256;
    nvp[b] = p;
  }
}

// ------- fused compact split into "hl" layout: text & text1 gathered to KC rows, + W -------
// dst row j (< KC) = split of src full row idx[b][j]; pad rows duplicate row 0 (finite,
// masked downstream). hl layout: hi at r*2048 + (k>>5)*64 + (k&31), lo at +32.
__device__ __forceinline__ void split_chunk(const float* __restrict__ srcRow,
                                            u16* __restrict__ dstRow, int kc) {
  f32x4 v0 = *(const f32x4*)(srcRow + kc);
  f32x4 v1 = *(const f32x4*)(srcRow + kc + 4);
  u16x8 h, l;
#pragma unroll
  for (int j = 0; j < 4; ++j) {
    u16 a = f2bf(v0[j]);
    h[j] = a;
    l[j] = f2bf(v0[j] - bf2f(a));
    u16 bb = f2bf(v1[j]);
    h[j + 4] = bb;
    l[j + 4] = f2bf(v1[j] - bf2f(bb));
  }
  const int off = ((kc >> 5) << 6) + (kc & 31);
  *(u16x8*)&dstRow[off] = h;
  *(u16x8*)&dstRow[off + 32] = l;
}

__global__ __launch_bounds__(256) void split_compact_kernel(
    const float* __restrict__ text, const float* __restrict__ t1, const float* __restrict__ W,
    const u16* __restrict__ idx,
    u16* __restrict__ text_c, u16* __restrict__ t1_c, u16* __restrict__ W_hl) {
  const int UB = KC * (ND / 8);            // units per batch (row-chunks of 8)
  const int U1 = NB * UB;                  // text units
  const int U2 = U1 + NB * UB;             // + t1
  const int U3 = U2 + ND * (ND / 8);       // + W
  int i = blockIdx.x * 256 + threadIdx.x;
  const int stride = gridDim.x * 256;
  for (; i < U3; i += stride) {
    if (i < U2) {
      const float* src = (i < U1) ? text : t1;
      u16* dst = (i < U1) ? text_c : t1_c;
      const int ii = (i < U1) ? i : i - U1;
      const int b = ii / UB;
      const int within = ii - b * UB;
      const int row = within >> 7;
      const int kc = (within & 127) << 3;
      const int srow = idx[(size_t)b * NS + row];
      split_chunk(src + ((size_t)b * NS + srow) * ND,
                  dst + ((size_t)b * KC + row) * 2048, kc);
    } else {
      const int ii = i - U2;
      const int row = ii >> 7;
      const int kc = (ii & 127) << 3;
      split_chunk(W + (size_t)row * ND, W_hl + (size_t)row * 2048, kc);
    }
  }
}

// ---- transpose from compact hl: t1Tc[b][d][j] = t1_c[b][j].hi[d]  (j already gathered) ----
// hl offset of dim d within a row is (d>>5)*64 + (d&31); for 32-aligned d0 and tx in 0..31
// that's a contiguous 32 x u16 run at (d0>>5)*64 + tx. Pad cols j>=nv carry dup-of-row-0
// values — harmless: PV's A operand (abf) is zero for k>=nv, and PV's gr<nv guard drops
// garbage output rows (all values finite).
__global__ __launch_bounds__(256) void gtrans2_kernel(
    const u16* __restrict__ t1_c, u16* __restrict__ t1Tc) {
  __shared__ u16 tile[32][33];
  const int b = blockIdx.z;
  const int j0 = blockIdx.x * 32, d0 = blockIdx.y * 32;
  const int tx = threadIdx.x, ty = threadIdx.y;  // (32,8)
  const int hlOff = (d0 >> 5) << 6;
#pragma unroll
  for (int k = 0; k < 4; ++k) {
    const int j = j0 + ty + 8 * k;
    tile[ty + 8 * k][tx] = t1_c[((size_t)b * KC + j) * 2048 + hlOff + tx];
  }
  __syncthreads();
#pragma unroll
  for (int k = 0; k < 4; ++k)
    t1Tc[((size_t)b * ND + d0 + ty + 8 * k) * KC + j0 + tx] = tile[tx][ty + 8 * k];
}

// ============ compact GEMM: 256x256 tile, 8 waves (2M x 4N), dbuf + global_load_lds =======
// Proven R3/R8 structure (2-barrier loop; R4/R9 showed phase-split grafts regress without
// the full 8-phase interleave). LDS tiles [256 rows][64 u16], chunk c of row r at byte
// r*128 + 16*(c ^ (r&7)) (XOR swizzle; 0 bank conflicts); per-lane GLOBAL source is
// pre-swizzled so global_load_lds' linear write lands swizzled.
// MODE 0 (K1): A=text_c, B=W_hl, 3-term split MFMA, out qc (compact hl).
// MODE 1 (K2): A=qc, B=t1_c, 3-term, out logitsC f32 compact.
// MODE 2 (PV): A=abf bf16, B=t1Tc bf16, 2xK MFMA, dynamic K, out0 scatter + bias.
template <int MODE>
__global__ __launch_bounds__(512, 2) void gemm_c_kernel(
    const u16* __restrict__ A, const u16* __restrict__ B,
    const u16* __restrict__ idx, const int* __restrict__ nv, const int* __restrict__ nvp,
    u16* __restrict__ outQ, float* __restrict__ outF, const float* __restrict__ bias) {
  constexpr int nTN = (MODE == 1) ? (KC / 256) : (ND / 256);
  constexpr int rowLen = (MODE == 2) ? KC : 2048;
  __shared__ __align__(16) u16 lds[2][2][16384];  // [dbuf][A/B][256*64] = 128 KiB
  const int t = threadIdx.x;
  const int bz = blockIdx.y;
  // XCD-aware bijective swizzle (m204 general form, any grid size)
  const int n = gridDim.x;
  const int q8 = n >> 3, r8 = n & 7, xb = (int)blockIdx.x & 7, kb = (int)blockIdx.x >> 3;
  const int xs = (xb < r8 ? xb * (q8 + 1) : r8 * (q8 + 1) + (xb - r8) * q8) + kb;
  const int tm = xs / nTN, tn = xs % nTN;
  const int rowA0 = tm * 256, rowB0 = tn * 256;
  const int nvpb = nvp[bz];
  if (rowA0 >= nvpb) return;
  if (MODE == 1 && rowB0 >= nvpb) return;

  const int lane = t & 63, w = t >> 6;   // 8 waves: 2M x 4N
  const int wr = w >> 2, wc = w & 3;
  const int fr = lane & 15, fq = lane >> 4;

  // staging: wave w covers rows w*32 + j*8 + lr; lane loads chunk (lane&7)^lr
  const int lr = lane >> 3;
  const int ch = (lane & 7) ^ lr;
  const int ra = rowA0 + w * 32 + lr;
  const int rb = rowB0 + w * 32 + lr;
  const u16* pA0;
  const u16* pB0;
  if (MODE == 0) {
    pA0 = A + ((size_t)bz * KC + ra) * rowLen + ch * 8;   // text_c
    pB0 = B + (size_t)rb * rowLen + ch * 8;               // W (no batch)
  } else if (MODE == 1) {
    pA0 = A + ((size_t)bz * KC + ra) * rowLen + ch * 8;   // qc
    pB0 = B + ((size_t)bz * KC + rb) * rowLen + ch * 8;   // t1_c
  } else {
    pA0 = A + ((size_t)bz * KC + ra) * rowLen + ch * 8;   // abf
    pB0 = B + ((size_t)bz * ND + rb) * rowLen + ch * 8;   // t1Tc
  }

  const int swz = (fr & 7) << 4;
  const int aOff = ((wr * 128 + fr) << 7) + ((fq << 4) ^ swz);
  const int bOff = ((wc * 64 + fr) << 7) + ((fq << 4) ^ swz);

  f32x4 acc[8][4] = {};

  const int nsteps = (MODE == 2) ? (nvpb >> 6) : 32;

#pragma unroll
  for (int j = 0; j < 4; ++j)
    gload16(pA0 + (size_t)(j * 8) * rowLen, (char*)&lds[0][0][0] + w * 4096 + j * 1024);
#pragma unroll
  for (int j = 0; j < 4; ++j)
    gload16(pB0 + (size_t)(j * 8) * rowLen, (char*)&lds[0][1][0] + w * 4096 + j * 1024);
  __syncthreads();

#pragma unroll 2
  for (int s = 0; s < nsteps; ++s) {
    const int cur = s & 1;
    if (s + 1 < nsteps) {
#pragma unroll
      for (int j = 0; j < 4; ++j)
        gload16(pA0 + (size_t)(j * 8) * rowLen + (s + 1) * 64,
                (char*)&lds[cur ^ 1][0][0] + w * 4096 + j * 1024);
#pragma unroll
      for (int j = 0; j < 4; ++j)
        gload16(pB0 + (size_t)(j * 8) * rowLen + (s + 1) * 64,
                (char*)&lds[cur ^ 1][1][0] + w * 4096 + j * 1024);
    }
    const char* bAc = (const char*)&lds[cur][0][0];
    const char* bBc = (const char*)&lds[cur][1][0];
    bf16x8 b0[4], b1[4];
#pragma unroll
    for (int ni = 0; ni < 4; ++ni) {
      const int ba = bOff + (ni << 11);
      b0[ni] = *(const bf16x8*)(bBc + ba);          // hi (split) / k 0..31 (pv)
      b1[ni] = *(const bf16x8*)(bBc + (ba ^ 64));   // lo (split) / k 32..63 (pv)
    }
#pragma unroll
    for (int mi = 0; mi < 8; ++mi) {
      const int aa = aOff + (mi << 11);
      bf16x8 a0 = *(const bf16x8*)(bAc + aa);
      bf16x8 a1 = *(const bf16x8*)(bAc + (aa ^ 64));
#pragma unroll
      for (int ni = 0; ni < 4; ++ni) {
        if (MODE < 2) {
          acc[mi][ni] = __builtin_amdgcn_mfma_f32_16x16x32_bf16(a0, b0[ni], acc[mi][ni], 0, 0, 0);
          acc[mi][ni] = __builtin_amdgcn_mfma_f32_16x16x32_bf16(a0, b1[ni], acc[mi][ni], 0, 0, 0);
          acc[mi][ni] = __builtin_amdgcn_mfma_f32_16x16x32_bf16(a1, b0[ni], acc[mi][ni], 0, 0, 0);
        } else {
          acc[mi][ni] = __builtin_amdgcn_mfma_f32_16x16x32_bf16(a0, b0[ni], acc[mi][ni], 0, 0, 0);
          acc[mi][ni] = __builtin_amdgcn_mfma_f32_16x16x32_bf16(a1, b1[ni], acc[mi][ni], 0, 0, 0);
        }
      }
    }
    __syncthreads();
  }

  // C/D layout (verified m89/m91): col = lane&15, row = (lane>>4)*4 + reg
  const int growBase = rowA0 + wr * 128 + fq * 4;
  const int gcolBase = rowB0 + wc * 64 + fr;
  const int nvb = nv[bz];
#pragma unroll
  for (int mi = 0; mi < 8; ++mi)
#pragma unroll
    for (int ni = 0; ni < 4; ++ni) {
      const int gc = gcolBase + ni * 16;
      float bv = 0.f;
      if (MODE == 2) bv = bias[gc];
#pragma unroll
      for (int r = 0; r < 4; ++r) {
        const int gr = growBase + mi * 16 + r;
        const float v = acc[mi][ni][r];
        if (MODE == 0) {
          const size_t base = ((size_t)bz * KC + gr) * 2048 + ((gc >> 5) << 6) + (gc & 31);
          const u16 h = f2bf(v);
          outQ[base] = h;
          outQ[base + 32] = f2bf(v - bf2f(h));
        } else if (MODE == 1) {
          outF[((size_t)bz * KC + gr) * KC + gc] = v;            // compact logits
        } else {
          if (gr < nvb) {
            const int sf = idx[(size_t)bz * NS + gr];
            outF[((size_t)bz * NS + sf) * 1024 + gc] = v + bv;   // scatter out0 row
          }
        }
      }
    }
}

// -------- softmax over compact logits; expand to full attn row; bias for masked rows --------
__global__ __launch_bounds__(256) void softmax_expand_kernel(
    const float* __restrict__ logitsC, const float* __restrict__ mask,
    const float* __restrict__ bias, float* __restrict__ out0, float* __restrict__ attn,
    const u16* __restrict__ pos, const int* __restrict__ nv, u16* __restrict__ abf) {
  const int row = blockIdx.x, b = row >> 11, s = row & 2047, t = threadIdx.x;
  float* p = attn + (size_t)row * NS;
  const float qm = mask[((size_t)b << 11) + s];
  if (qm == 0.f) {
    f32x4 z = {0.f, 0.f, 0.f, 0.f};
    ((f32x4*)p)[2 * t] = z;
    ((f32x4*)p)[2 * t + 1] = z;
    float* o = out0 + (((size_t)b << 11) + s) * ND;
    ((f32x4*)o)[t] = ((const f32x4*)bias)[t];
    return;
  }
  const int nvb = nv[b];
  const int jq = pos[((size_t)b << 11) + s];
  const float* lrow = logitsC + ((size_t)b * KC + jq) * KC;
  float v[8];
#pragma unroll
  for (int j = 0; j < 8; ++j) {
    const int jj = t * 8 + j;
    v[j] = (jj < nvb) ? lrow[jj] : -3.0e38f;
  }
  float mx = v[0];
#pragma unroll
  for (int j = 1; j < 8; ++j) mx = fmaxf(mx, v[j]);
#pragma unroll
  for (int o = 32; o > 0; o >>= 1) mx = fmaxf(mx, __shfl_xor(mx, o));
  __shared__ float red[4];
  __shared__ float esm[KC];
  if ((t & 63) == 0) red[t >> 6] = mx;
  __syncthreads();
  mx = fmaxf(fmaxf(red[0], red[1]), fmaxf(red[2], red[3]));
  float e[8];
  float sum = 0.f;
#pragma unroll
  for (int j = 0; j < 8; ++j) {
    e[j] = (t * 8 + j < nvb) ? __expf(v[j] - mx) : 0.f;
    sum += e[j];
  }
#pragma unroll
  for (int o = 32; o > 0; o >>= 1) sum += __shfl_xor(sum, o);
  __syncthreads();
  if ((t & 63) == 0) red[t >> 6] = sum;
  __syncthreads();
  sum = red[0] + red[1] + red[2] + red[3];
  const float sc = 1.0f / sum;
  if (t < KC / 8) {
    u16x8 ub;
#pragma unroll
    for (int j = 0; j < 8; ++j) {
      const float ev = e[j] * sc;
      esm[t * 8 + j] = ev;
      ub[j] = f2bf(ev);
    }
    *(u16x8*)(abf + ((size_t)b * KC + jq) * KC + t * 8) = ub;
  }
  __syncthreads();
  const float* km = mask + ((size_t)b << 11);
  const u16* pp = pos + ((size_t)b << 11);
  const u16x8 pv8 = *(const u16x8*)&pp[t * 8];
  const f32x4 km0 = ((const f32x4*)km)[2 * t];
  const f32x4 km1 = ((const f32x4*)km)[2 * t + 1];
#pragma unroll
  for (int h = 0; h < 2; ++h) {
    const f32x4 kmv = h ? km1 : km0;
    f32x4 ov;
#pragma unroll
    for (int j = 0; j < 4; ++j) {
      int ip = pv8[h * 4 + j];
      if (ip >= KC) ip = 0;  // speculation-safe clamp (valid tokens always < nv <= KC)
      ov[j] = (kmv[j] != 0.f) ? esm[ip] : 0.f;
    }
    ((f32x4*)p)[2 * t + h] = ov;
  }
}

extern "C" void kernel_launch(void* const* d_in, const int* in_sizes, int n_in,
                              void* d_out, int out_size, void* d_ws, size_t ws_size,
                              hipStream_t stream) {
  const float* text = (const float*)d_in[0];
  const float* text1 = (const float*)d_in[1];
  const float* mask = (const float*)d_in[2];
  const float* W = (const float*)d_in[3];
  const float* bias = (const float*)d_in[4];

  float* out0 = (float*)d_out;                       // [8,2048,1024] f32
  float* attn = out0 + (size_t)NB * NS * ND;         // [8,2048,2048] f32

  // choreography:
  //  attn region: text_c (40MB compact hl) -> K1 consumes -> softmax writes full attn rows
  //  out0 region: qc (compact q hl, 40MB) -> dead after K2 -> PV + softmax write out0
  //  ws: t1_c(40MB) | W_hl(4MB) | t1Tc(21MB) | logitsC(52MB) | idx/pos/nv/nvp;
  //      abf (26MB) overlays t1_c (dead after K2)
  u16* text_c = (u16*)attn;                           // [8][KC][2048]
  u16* qc = (u16*)out0;                               // [8][KC][2048]
  u16* wsp = (u16*)d_ws;
  u16* t1_c = wsp;                                    // [8][KC][2048]
  u16* W_hl = t1_c + (size_t)NB * KC * 2048;          // [1024][2048]
  u16* t1Tc = W_hl + (size_t)ND * 2048;               // [8][1024][KC]
  float* logitsC = (float*)(t1Tc + (size_t)NB * ND * KC);  // [8][KC][KC] f32
  u16* idx = (u16*)(logitsC + (size_t)NB * KC * KC);  // [8][2048]
  u16* pos = idx + (size_t)NB * NS;                   // [8][2048]
  int* nv = (int*)(pos + (size_t)NB * NS);            // [8]
  int* nvp = nv + NB;                                 // [8]
  u16* abf = t1_c;                                    // [8][KC][KC] bf16, overlays t1_c

  scan_kernel<<<NB, 256, 0, stream>>>(mask, idx, pos, nv, nvp);
  split_compact_kernel<<<2048, 256, 0, stream>>>(text, text1, W, idx, text_c, t1_c, W_hl);
  gtrans2_kernel<<<dim3(KC / 32, ND / 32, NB), dim3(32, 8), 0, stream>>>(t1_c, t1Tc);

  // K1: qc = text_c @ W^T  (M=nvp<=KC compact, N=1024, K=1024) -> qc
  gemm_c_kernel<0><<<dim3((KC / 256) * (ND / 256), NB), 512, 0, stream>>>(
      text_c, W_hl, idx, nv, nvp, qc, nullptr, nullptr);

  // K2: logitsC = qc @ t1_c^T (M,N=nvp compact, K=1024) -> compact f32
  gemm_c_kernel<1><<<dim3((KC / 256) * (KC / 256), NB), 512, 0, stream>>>(
      qc, t1_c, idx, nv, nvp, nullptr, logitsC, nullptr);

  // K3: softmax over compact logits; expand full attn rows; abf compact; bias rows in out0
  softmax_expand_kernel<<<NB * NS, 256, 0, stream>>>(
      logitsC, mask, bias, out0, attn, pos, nv, abf);

  // K4: out0[idx] = abf @ t1Tc^T + bias (M=nvp compact, N=1024, K=nvp compact)
  gemm_c_kernel<2><<<dim3((KC / 256) * (ND / 256), NB), 512, 0, stream>>>(
      abf, t1Tc, idx, nv, nvp, nullptr, out0, bias);
}